// Round 2
// baseline (533.535 us; speedup 1.0000x reference)
//
#include <hip/hip_runtime.h>

#define NN 100000
#define NE 600000

// ---------------- degree / CSR build ----------------

__global__ void k_init_deg(int* __restrict__ deg, int n) {
    int i = blockIdx.x * 256 + threadIdx.x;
    if (i < n) deg[i] = 0;
}

__global__ void k_deg_count(const int* __restrict__ col, int* __restrict__ deg, int E) {
    int e = blockIdx.x * 256 + threadIdx.x;
    if (e < E) atomicAdd(&deg[col[e]], 1);
}

__global__ void k_dinv(const int* __restrict__ deg, float* __restrict__ dinv, int n) {
    int i = blockIdx.x * 256 + threadIdx.x;
    if (i < n) dinv[i] = rsqrtf((float)(deg[i] + 1));   // +1: self-loop
}

// per-block exclusive scan of deg -> offs (block-local), block totals -> bsums
__global__ void k_scan1(const int* __restrict__ deg, int* __restrict__ offs,
                        int* __restrict__ bsums, int n) {
    __shared__ int s[256];
    int t = threadIdx.x;
    int i = blockIdx.x * 256 + t;
    int v = (i < n) ? deg[i] : 0;
    s[t] = v;
    __syncthreads();
    for (int off = 1; off < 256; off <<= 1) {
        int x = (t >= off) ? s[t - off] : 0;
        __syncthreads();
        s[t] += x;
        __syncthreads();
    }
    if (i < n) offs[i] = s[t] - v;           // exclusive within block
    if (t == 255) bsums[blockIdx.x] = s[255]; // block total
}

// single-block exclusive scan of block sums (nb <= 512)
__global__ void k_scan2(int* __restrict__ bsums, int nb) {
    __shared__ int s[512];
    int t = threadIdx.x;
    int v = (t < nb) ? bsums[t] : 0;
    s[t] = v;
    __syncthreads();
    for (int off = 1; off < 512; off <<= 1) {
        int x = (t >= off) ? s[t - off] : 0;
        __syncthreads();
        s[t] += x;
        __syncthreads();
    }
    if (t < nb) bsums[t] = s[t] - v;         // exclusive
}

__global__ void k_scan3(int* __restrict__ offs, const int* __restrict__ bsums,
                        int* __restrict__ cursor, int n) {
    int i = blockIdx.x * 256 + threadIdx.x;
    if (i < n) {
        int o = offs[i] + bsums[i >> 8];
        offs[i] = o;
        cursor[i] = o;
    }
}

__global__ void k_fill(const int* __restrict__ row, const int* __restrict__ col,
                       int* __restrict__ cursor, int* __restrict__ srcs, int E) {
    int e = blockIdx.x * 256 + threadIdx.x;
    if (e < E) {
        int p = atomicAdd(&cursor[col[e]], 1);
        srcs[p] = row[e];
    }
}

// ---------------- GEMM: G = (H @ W) * dinv[row]  ----------------
// H: [n][128] row-major, W: [128][DOUT] row-major, G: [n][DOUT]
// block: 256 threads, tile 128 rows x DOUT cols, per-thread 8 x (DOUT/16)

template <int DOUT>
__global__ __launch_bounds__(256)
void k_gemm(const float* __restrict__ H, const float* __restrict__ W,
            const float* __restrict__ dinv, float* __restrict__ G, int n) {
    constexpr int TC = DOUT / 16;          // 8 for 128, 4 for 64
    __shared__ float hs[128][34];          // pad 34: 2-way bank conflicts only (free)
    __shared__ float wk[32][DOUT];

    int tid = threadIdx.x;
    int r0 = blockIdx.x * 128;
    int trow = (tid >> 4) << 3;            // (tid/16)*8
    int tcol = (tid & 15) * TC;

    float acc[8][TC];
#pragma unroll
    for (int i = 0; i < 8; i++)
#pragma unroll
        for (int j = 0; j < TC; j++) acc[i][j] = 0.f;

    for (int k0 = 0; k0 < 128; k0 += 32) {
        __syncthreads();   // protect LDS from previous iteration's readers
        // stage h tile: 128 rows x 32 k  (1024 float4, 4 per thread)
#pragma unroll
        for (int i = 0; i < 4; i++) {
            int idx = tid + i * 256;
            int r = idx >> 3;
            int kv = idx & 7;
            int gr = r0 + r;
            float4 v = make_float4(0.f, 0.f, 0.f, 0.f);
            if (gr < n) v = *(const float4*)&H[(size_t)gr * 128 + k0 + kv * 4];
            float2* p = (float2*)&hs[r][kv * 4];   // 8B-aligned (34*4=136, 8|136)
            p[0] = make_float2(v.x, v.y);
            p[1] = make_float2(v.z, v.w);
        }
        // stage W panel: 32 k x DOUT  (DOUT/32 float4 per thread)
#pragma unroll
        for (int i = 0; i < DOUT / 32; i++) {
            int idx = tid + i * 256;
            int k = idx / (DOUT / 4);
            int cv = idx % (DOUT / 4);
            *(float4*)&wk[k][cv * 4] = *(const float4*)&W[(size_t)(k0 + k) * DOUT + cv * 4];
        }
        __syncthreads();
#pragma unroll 8
        for (int k = 0; k < 32; k++) {
            float a[8];
#pragma unroll
            for (int i = 0; i < 8; i++) a[i] = hs[trow + i][k];
            float w[TC];
            *(float4*)&w[0] = *(const float4*)&wk[k][tcol];
            if (TC == 8) *(float4*)&w[4] = *(const float4*)&wk[k][tcol + 4];
#pragma unroll
            for (int i = 0; i < 8; i++)
#pragma unroll
                for (int j = 0; j < TC; j++) acc[i][j] = fmaf(a[i], w[j], acc[i][j]);
        }
    }
    // epilogue: scale by dinv[row], store
#pragma unroll
    for (int i = 0; i < 8; i++) {
        int gr = r0 + trow + i;
        if (gr < n) {
            float di = dinv[gr];
#pragma unroll
            for (int j4 = 0; j4 < TC; j4 += 4) {
                float4 o;
                o.x = acc[i][j4 + 0] * di;
                o.y = acc[i][j4 + 1] * di;
                o.z = acc[i][j4 + 2] * di;
                o.w = acc[i][j4 + 3] * di;
                *(float4*)&G[(size_t)gr * DOUT + tcol + j4] = o;
            }
        }
    }
}

// ---------------- aggregation (gather) ----------------
// one wave (64 lanes) per node; D=128 -> float2 per lane

__global__ __launch_bounds__(256)
void k_agg_relu(const float* __restrict__ G, const int* __restrict__ offs,
                const int* __restrict__ deg, const int* __restrict__ srcs,
                const float* __restrict__ dinv, const float* __restrict__ bias,
                float* __restrict__ out, int n) {
    int wid = (blockIdx.x * 256 + threadIdx.x) >> 6;
    int lane = threadIdx.x & 63;
    if (wid >= n) return;
    const float2* G2 = (const float2*)G;
    float2 acc = G2[(size_t)wid * 64 + lane];   // self-loop contribution
    int start = offs[wid];
    int cnt = deg[wid];
    for (int j = 0; j < cnt; j++) {
        int s = srcs[start + j];
        float2 v = G2[(size_t)s * 64 + lane];
        acc.x += v.x;
        acc.y += v.y;
    }
    float di = dinv[wid];
    float2 bb = ((const float2*)bias)[lane];
    float2 r;
    r.x = fmaxf(fmaf(acc.x, di, bb.x), 0.f);
    r.y = fmaxf(fmaf(acc.y, di, bb.y), 0.f);
    ((float2*)out)[(size_t)wid * 64 + lane] = r;
}

// final layer: D=64, one lane per feature, fused log_softmax
__global__ __launch_bounds__(256)
void k_agg_softmax(const float* __restrict__ G, const int* __restrict__ offs,
                   const int* __restrict__ deg, const int* __restrict__ srcs,
                   const float* __restrict__ dinv, const float* __restrict__ bias,
                   float* __restrict__ out, int n) {
    int wid = (blockIdx.x * 256 + threadIdx.x) >> 6;
    int lane = threadIdx.x & 63;
    if (wid >= n) return;
    float acc = G[(size_t)wid * 64 + lane];     // self-loop
    int start = offs[wid];
    int cnt = deg[wid];
    for (int j = 0; j < cnt; j++) {
        int s = srcs[start + j];
        acc += G[(size_t)s * 64 + lane];
    }
    float t = fmaf(acc, dinv[wid], bias[lane]);
    float m = t;
    for (int off = 32; off; off >>= 1) m = fmaxf(m, __shfl_xor(m, off, 64));
    float e = expf(t - m);
    float ssum = e;
    for (int off = 32; off; off >>= 1) ssum += __shfl_xor(ssum, off, 64);
    out[(size_t)wid * 64 + lane] = t - m - logf(ssum);
}

// ---------------- launch ----------------

extern "C" void kernel_launch(void* const* d_in, const int* in_sizes, int n_in,
                              void* d_out, int out_size, void* d_ws, size_t ws_size,
                              hipStream_t stream) {
    const float* x  = (const float*)d_in[0];
    const int*   ei = (const int*)d_in[1];
    const int*   row = ei;             // edge_index[0]: source
    const int*   col = ei + NE;        // edge_index[1]: destination
    const float* W1 = (const float*)d_in[2];
    const float* b1 = (const float*)d_in[3];
    const float* W2 = (const float*)d_in[4];
    const float* b2 = (const float*)d_in[5];
    const float* W3 = (const float*)d_in[6];
    const float* b3 = (const float*)d_in[7];
    float* outp = (float*)d_out;

    char* ws = (char*)d_ws;
    size_t off = 0;
    auto alloc = [&](size_t bytes) -> void* {
        void* p = (void*)(ws + off);
        off += (bytes + 255) & ~(size_t)255;
        return p;
    };
    float* dinv  = (float*)alloc((size_t)NN * 4);
    float* bufA  = (float*)alloc((size_t)NN * 128 * 4);
    float* bufB  = (float*)alloc((size_t)NN * 128 * 4);
    int*   deg   = (int*)alloc((size_t)NN * 4);
    int*   offs  = (int*)alloc((size_t)NN * 4);
    int*   cursor= (int*)alloc((size_t)NN * 4);
    int*   bsums = (int*)alloc(1024 * 4);
    int*   srcs  = (int*)alloc((size_t)NE * 4);

    int nbN = (NN + 255) / 256;   // 391
    int nbE = (NE + 255) / 256;

    k_init_deg <<<nbN, 256, 0, stream>>>(deg, NN);
    k_deg_count<<<nbE, 256, 0, stream>>>(col, deg, NE);
    k_dinv     <<<nbN, 256, 0, stream>>>(deg, dinv, NN);
    k_scan1    <<<nbN, 256, 0, stream>>>(deg, offs, bsums, NN);
    k_scan2    <<<1,   512, 0, stream>>>(bsums, nbN);
    k_scan3    <<<nbN, 256, 0, stream>>>(offs, bsums, cursor, NN);
    k_fill     <<<nbE, 256, 0, stream>>>(row, col, cursor, srcs, NE);

    int gb = (NN + 127) / 128;            // 782
    int ab = (NN * 64 + 255) / 256;       // 25000 (wave per node)

    // layer 1: x -> bufA(g) -> bufB(h1)
    k_gemm<128><<<gb, 256, 0, stream>>>(x, W1, dinv, bufA, NN);
    k_agg_relu <<<ab, 256, 0, stream>>>(bufA, offs, deg, srcs, dinv, b1, bufB, NN);
    // layer 2: bufB -> bufA(g) -> bufB(h2)
    k_gemm<128><<<gb, 256, 0, stream>>>(bufB, W2, dinv, bufA, NN);
    k_agg_relu <<<ab, 256, 0, stream>>>(bufA, offs, deg, srcs, dinv, b2, bufB, NN);
    // layer 3: bufB -> bufA(g, 64-wide) -> out (log_softmax)
    k_gemm<64> <<<gb, 256, 0, stream>>>(bufB, W3, dinv, bufA, NN);
    k_agg_softmax<<<ab, 256, 0, stream>>>(bufA, offs, deg, srcs, dinv, b3, outp, NN);
}

// Round 4
// 463.874 us; speedup vs baseline: 1.1502x; 1.1502x over previous
//
#include <hip/hip_runtime.h>

#define NN 100000
#define NE 600000

// ---------------- degree / CSR build ----------------

__global__ void k_init_deg(int* __restrict__ deg, int n) {
    int i = blockIdx.x * 256 + threadIdx.x;
    if (i < n) deg[i] = 0;
}

__global__ void k_deg_count(const int* __restrict__ col, int* __restrict__ deg, int E) {
    int e = blockIdx.x * 256 + threadIdx.x;
    if (e < E) atomicAdd(&deg[col[e]], 1);
}

__global__ void k_dinv(const int* __restrict__ deg, float* __restrict__ dinv, int n) {
    int i = blockIdx.x * 256 + threadIdx.x;
    if (i < n) dinv[i] = rsqrtf((float)(deg[i] + 1));   // +1: self-loop
}

// per-block exclusive scan of deg -> offs (block-local), block totals -> bsums
__global__ void k_scan1(const int* __restrict__ deg, int* __restrict__ offs,
                        int* __restrict__ bsums, int n) {
    __shared__ int s[256];
    int t = threadIdx.x;
    int i = blockIdx.x * 256 + t;
    int v = (i < n) ? deg[i] : 0;
    s[t] = v;
    __syncthreads();
    for (int off = 1; off < 256; off <<= 1) {
        int x = (t >= off) ? s[t - off] : 0;
        __syncthreads();
        s[t] += x;
        __syncthreads();
    }
    if (i < n) offs[i] = s[t] - v;           // exclusive within block
    if (t == 255) bsums[blockIdx.x] = s[255]; // block total
}

// single-block exclusive scan of block sums (nb <= 512)
__global__ void k_scan2(int* __restrict__ bsums, int nb) {
    __shared__ int s[512];
    int t = threadIdx.x;
    int v = (t < nb) ? bsums[t] : 0;
    s[t] = v;
    __syncthreads();
    for (int off = 1; off < 512; off <<= 1) {
        int x = (t >= off) ? s[t - off] : 0;
        __syncthreads();
        s[t] += x;
        __syncthreads();
    }
    if (t < nb) bsums[t] = s[t] - v;         // exclusive
}

__global__ void k_scan3(int* __restrict__ offs, const int* __restrict__ bsums,
                        int* __restrict__ cursor, int n) {
    int i = blockIdx.x * 256 + threadIdx.x;
    if (i < n) {
        int o = offs[i] + bsums[i >> 8];
        offs[i] = o;
        cursor[i] = o;
    }
}

__global__ void k_fill(const int* __restrict__ row, const int* __restrict__ col,
                       int* __restrict__ cursor, int* __restrict__ srcs, int E) {
    int e = blockIdx.x * 256 + threadIdx.x;
    if (e < E) {
        int p = atomicAdd(&cursor[col[e]], 1);
        srcs[p] = row[e];
    }
}

// ---------------- GEMM: G = (H @ W) * dinv[row]  ----------------
// H: [n][128] row-major, W: [128][DOUT] row-major, G: [n][DOUT]
// block: 256 threads, tile 128 rows x DOUT cols, per-thread 8 x (DOUT/16)

template <int DOUT>
__global__ __launch_bounds__(256)
void k_gemm(const float* __restrict__ H, const float* __restrict__ W,
            const float* __restrict__ dinv, float* __restrict__ G, int n) {
    constexpr int TC = DOUT / 16;          // 8 for 128, 4 for 64
    __shared__ float hs[128][34];          // pad 34: 2-way bank conflicts only (free)
    __shared__ float wk[32][DOUT];

    int tid = threadIdx.x;
    int r0 = blockIdx.x * 128;
    int trow = (tid >> 4) << 3;            // (tid/16)*8
    int tcol = (tid & 15) * TC;

    float acc[8][TC];
#pragma unroll
    for (int i = 0; i < 8; i++)
#pragma unroll
        for (int j = 0; j < TC; j++) acc[i][j] = 0.f;

    for (int k0 = 0; k0 < 128; k0 += 32) {
        __syncthreads();   // protect LDS from previous iteration's readers
        // stage h tile: 128 rows x 32 k  (1024 float4, 4 per thread)
#pragma unroll
        for (int i = 0; i < 4; i++) {
            int idx = tid + i * 256;
            int r = idx >> 3;
            int kv = idx & 7;
            int gr = r0 + r;
            float4 v = make_float4(0.f, 0.f, 0.f, 0.f);
            if (gr < n) v = *(const float4*)&H[(size_t)gr * 128 + k0 + kv * 4];
            float2* p = (float2*)&hs[r][kv * 4];   // 8B-aligned (34*4=136, 8|136)
            p[0] = make_float2(v.x, v.y);
            p[1] = make_float2(v.z, v.w);
        }
        // stage W panel: 32 k x DOUT  (DOUT/32 float4 per thread)
#pragma unroll
        for (int i = 0; i < DOUT / 32; i++) {
            int idx = tid + i * 256;
            int k = idx / (DOUT / 4);
            int cv = idx % (DOUT / 4);
            *(float4*)&wk[k][cv * 4] = *(const float4*)&W[(size_t)(k0 + k) * DOUT + cv * 4];
        }
        __syncthreads();
#pragma unroll 8
        for (int k = 0; k < 32; k++) {
            float a[8];
#pragma unroll
            for (int i = 0; i < 8; i++) a[i] = hs[trow + i][k];
            float w[TC];
            *(float4*)&w[0] = *(const float4*)&wk[k][tcol];
            if (TC == 8) *(float4*)&w[4] = *(const float4*)&wk[k][tcol + 4];
#pragma unroll
            for (int i = 0; i < 8; i++)
#pragma unroll
                for (int j = 0; j < TC; j++) acc[i][j] = fmaf(a[i], w[j], acc[i][j]);
        }
    }
    // epilogue: scale by dinv[row], store
#pragma unroll
    for (int i = 0; i < 8; i++) {
        int gr = r0 + trow + i;
        if (gr < n) {
            float di = dinv[gr];
#pragma unroll
            for (int j4 = 0; j4 < TC; j4 += 4) {
                float4 o;
                o.x = acc[i][j4 + 0] * di;
                o.y = acc[i][j4 + 1] * di;
                o.z = acc[i][j4 + 2] * di;
                o.w = acc[i][j4 + 3] * di;
                *(float4*)&G[(size_t)gr * DOUT + tcol + j4] = o;
            }
        }
    }
}

// ---------------- aggregation (gather) ----------------
// one wave (64 lanes) per node; D=128 -> float2 per lane
// unroll-by-4: 4 independent srcs loads -> 4 independent gathers -> 4 acc chains
// (baseline was latency-bound: VALUBusy 11%, 2.77 TB/s; this quadruples MLP)

__global__ __launch_bounds__(256)
void k_agg_relu(const float* __restrict__ G, const int* __restrict__ offs,
                const int* __restrict__ deg, const int* __restrict__ srcs,
                const float* __restrict__ dinv, const float* __restrict__ bias,
                float* __restrict__ out, int n) {
    int wid = (blockIdx.x * 256 + threadIdx.x) >> 6;
    int lane = threadIdx.x & 63;
    if (wid >= n) return;
    const float2* G2 = (const float2*)G;
    float2 a0 = G2[(size_t)wid * 64 + lane];   // self-loop contribution
    float2 a1 = make_float2(0.f, 0.f);
    float2 a2 = make_float2(0.f, 0.f);
    float2 a3 = make_float2(0.f, 0.f);
    int start = offs[wid];
    int cnt = deg[wid];
    int j = 0;
    for (; j + 4 <= cnt; j += 4) {
        int s0 = srcs[start + j + 0];
        int s1 = srcs[start + j + 1];
        int s2 = srcs[start + j + 2];
        int s3 = srcs[start + j + 3];
        float2 v0 = G2[(size_t)s0 * 64 + lane];
        float2 v1 = G2[(size_t)s1 * 64 + lane];
        float2 v2 = G2[(size_t)s2 * 64 + lane];
        float2 v3 = G2[(size_t)s3 * 64 + lane];
        a0.x += v0.x; a0.y += v0.y;
        a1.x += v1.x; a1.y += v1.y;
        a2.x += v2.x; a2.y += v2.y;
        a3.x += v3.x; a3.y += v3.y;
    }
    for (; j < cnt; j++) {
        int s = srcs[start + j];
        float2 v = G2[(size_t)s * 64 + lane];
        a0.x += v.x; a0.y += v.y;
    }
    float2 acc;
    acc.x = (a0.x + a1.x) + (a2.x + a3.x);
    acc.y = (a0.y + a1.y) + (a2.y + a3.y);
    float di = dinv[wid];
    float2 bb = ((const float2*)bias)[lane];
    float2 r;
    r.x = fmaxf(fmaf(acc.x, di, bb.x), 0.f);
    r.y = fmaxf(fmaf(acc.y, di, bb.y), 0.f);
    ((float2*)out)[(size_t)wid * 64 + lane] = r;
}

// final layer: D=64, one lane per feature, fused log_softmax
__global__ __launch_bounds__(256)
void k_agg_softmax(const float* __restrict__ G, const int* __restrict__ offs,
                   const int* __restrict__ deg, const int* __restrict__ srcs,
                   const float* __restrict__ dinv, const float* __restrict__ bias,
                   float* __restrict__ out, int n) {
    int wid = (blockIdx.x * 256 + threadIdx.x) >> 6;
    int lane = threadIdx.x & 63;
    if (wid >= n) return;
    float a0 = G[(size_t)wid * 64 + lane];     // self-loop
    float a1 = 0.f, a2 = 0.f, a3 = 0.f;
    int start = offs[wid];
    int cnt = deg[wid];
    int j = 0;
    for (; j + 4 <= cnt; j += 4) {
        int s0 = srcs[start + j + 0];
        int s1 = srcs[start + j + 1];
        int s2 = srcs[start + j + 2];
        int s3 = srcs[start + j + 3];
        a0 += G[(size_t)s0 * 64 + lane];
        a1 += G[(size_t)s1 * 64 + lane];
        a2 += G[(size_t)s2 * 64 + lane];
        a3 += G[(size_t)s3 * 64 + lane];
    }
    for (; j < cnt; j++) {
        int s = srcs[start + j];
        a0 += G[(size_t)s * 64 + lane];
    }
    float acc = (a0 + a1) + (a2 + a3);
    float t = fmaf(acc, dinv[wid], bias[lane]);
    float m = t;
    for (int off = 32; off; off >>= 1) m = fmaxf(m, __shfl_xor(m, off, 64));
    float e = expf(t - m);
    float ssum = e;
    for (int off = 32; off; off >>= 1) ssum += __shfl_xor(ssum, off, 64);
    out[(size_t)wid * 64 + lane] = t - m - logf(ssum);
}

// ---------------- launch ----------------

extern "C" void kernel_launch(void* const* d_in, const int* in_sizes, int n_in,
                              void* d_out, int out_size, void* d_ws, size_t ws_size,
                              hipStream_t stream) {
    const float* x  = (const float*)d_in[0];
    const int*   ei = (const int*)d_in[1];
    const int*   row = ei;             // edge_index[0]: source
    const int*   col = ei + NE;        // edge_index[1]: destination
    const float* W1 = (const float*)d_in[2];
    const float* b1 = (const float*)d_in[3];
    const float* W2 = (const float*)d_in[4];
    const float* b2 = (const float*)d_in[5];
    const float* W3 = (const float*)d_in[6];
    const float* b3 = (const float*)d_in[7];
    float* outp = (float*)d_out;

    char* ws = (char*)d_ws;
    size_t off = 0;
    auto alloc = [&](size_t bytes) -> void* {
        void* p = (void*)(ws + off);
        off += (bytes + 255) & ~(size_t)255;
        return p;
    };
    float* dinv  = (float*)alloc((size_t)NN * 4);
    float* bufA  = (float*)alloc((size_t)NN * 128 * 4);
    float* bufB  = (float*)alloc((size_t)NN * 128 * 4);
    int*   deg   = (int*)alloc((size_t)NN * 4);
    int*   offs  = (int*)alloc((size_t)NN * 4);
    int*   cursor= (int*)alloc((size_t)NN * 4);
    int*   bsums = (int*)alloc(1024 * 4);
    int*   srcs  = (int*)alloc((size_t)NE * 4);

    int nbN = (NN + 255) / 256;   // 391
    int nbE = (NE + 255) / 256;

    k_init_deg <<<nbN, 256, 0, stream>>>(deg, NN);
    k_deg_count<<<nbE, 256, 0, stream>>>(col, deg, NE);
    k_dinv     <<<nbN, 256, 0, stream>>>(deg, dinv, NN);
    k_scan1    <<<nbN, 256, 0, stream>>>(deg, offs, bsums, NN);
    k_scan2    <<<1,   512, 0, stream>>>(bsums, nbN);
    k_scan3    <<<nbN, 256, 0, stream>>>(offs, bsums, cursor, NN);
    k_fill     <<<nbE, 256, 0, stream>>>(row, col, cursor, srcs, NE);

    int gb = (NN + 127) / 128;            // 782
    int ab = (NN * 64 + 255) / 256;       // 25000 (wave per node)

    // layer 1: x -> bufA(g) -> bufB(h1)
    k_gemm<128><<<gb, 256, 0, stream>>>(x, W1, dinv, bufA, NN);
    k_agg_relu <<<ab, 256, 0, stream>>>(bufA, offs, deg, srcs, dinv, b1, bufB, NN);
    // layer 2: bufB -> bufA(g) -> bufB(h2)
    k_gemm<128><<<gb, 256, 0, stream>>>(bufB, W2, dinv, bufA, NN);
    k_agg_relu <<<ab, 256, 0, stream>>>(bufA, offs, deg, srcs, dinv, b2, bufB, NN);
    // layer 3: bufB -> bufA(g, 64-wide) -> out (log_softmax)
    k_gemm<64> <<<gb, 256, 0, stream>>>(bufB, W3, dinv, bufA, NN);
    k_agg_softmax<<<ab, 256, 0, stream>>>(bufA, offs, deg, srcs, dinv, b3, outp, NN);
}

// Round 6
// 386.461 us; speedup vs baseline: 1.3806x; 1.2003x over previous
//
#include <hip/hip_runtime.h>

#define NN 100000
#define NE 600000

typedef unsigned short u16;
typedef float f32x4 __attribute__((ext_vector_type(4)));
typedef short s16x8 __attribute__((ext_vector_type(8)));
typedef u16 u16x8 __attribute__((ext_vector_type(8)));

__device__ inline u16 f2bf(float f) {            // fp32 -> bf16 RNE
    unsigned u = __float_as_uint(f);
    return (u16)((u + 0x7FFFu + ((u >> 16) & 1u)) >> 16);
}

// ---------------- degree / CSR build ----------------

__global__ void k_init_deg(int* __restrict__ deg, int n) {
    int i = blockIdx.x * 256 + threadIdx.x;
    if (i < n) deg[i] = 0;
}

__global__ void k_deg_count(const int* __restrict__ col, int* __restrict__ deg, int E) {
    int e = blockIdx.x * 256 + threadIdx.x;
    if (e < E) atomicAdd(&deg[col[e]], 1);
}

__global__ void k_dinv(const int* __restrict__ deg, float* __restrict__ dinv, int n) {
    int i = blockIdx.x * 256 + threadIdx.x;
    if (i < n) dinv[i] = rsqrtf((float)(deg[i] + 1));   // +1: self-loop
}

__global__ void k_scan1(const int* __restrict__ deg, int* __restrict__ offs,
                        int* __restrict__ bsums, int n) {
    __shared__ int s[256];
    int t = threadIdx.x;
    int i = blockIdx.x * 256 + t;
    int v = (i < n) ? deg[i] : 0;
    s[t] = v;
    __syncthreads();
    for (int off = 1; off < 256; off <<= 1) {
        int x = (t >= off) ? s[t - off] : 0;
        __syncthreads();
        s[t] += x;
        __syncthreads();
    }
    if (i < n) offs[i] = s[t] - v;
    if (t == 255) bsums[blockIdx.x] = s[255];
}

__global__ void k_scan2(int* __restrict__ bsums, int nb) {
    __shared__ int s[512];
    int t = threadIdx.x;
    int v = (t < nb) ? bsums[t] : 0;
    s[t] = v;
    __syncthreads();
    for (int off = 1; off < 512; off <<= 1) {
        int x = (t >= off) ? s[t - off] : 0;
        __syncthreads();
        s[t] += x;
        __syncthreads();
    }
    if (t < nb) bsums[t] = s[t] - v;
}

__global__ void k_scan3(int* __restrict__ offs, const int* __restrict__ bsums,
                        int* __restrict__ cursor, int n) {
    int i = blockIdx.x * 256 + threadIdx.x;
    if (i < n) {
        int o = offs[i] + bsums[i >> 8];
        offs[i] = o;
        cursor[i] = o;
    }
}

__global__ void k_fill(const int* __restrict__ row, const int* __restrict__ col,
                       int* __restrict__ cursor, int* __restrict__ srcs, int E) {
    int e = blockIdx.x * 256 + threadIdx.x;
    if (e < E) {
        int p = atomicAdd(&cursor[col[e]], 1);
        srcs[p] = row[e];
    }
}

// ---------------- fp32 -> bf16 conversion (x only; 8 elems/thread) ----------------

__global__ __launch_bounds__(256)
void k_cvt_bf16(const float* __restrict__ in, u16* __restrict__ out, int n8) {
    int i = blockIdx.x * 256 + threadIdx.x;
    if (i >= n8) return;
    const float4* p = (const float4*)in;
    float4 v0 = p[i * 2], v1 = p[i * 2 + 1];
    u16x8 r;
    r[0] = f2bf(v0.x); r[1] = f2bf(v0.y); r[2] = f2bf(v0.z); r[3] = f2bf(v0.w);
    r[4] = f2bf(v1.x); r[5] = f2bf(v1.y); r[6] = f2bf(v1.z); r[7] = f2bf(v1.w);
    ((u16x8*)out)[i] = r;
}

// ---------------- W pack: fp32 [128][DOUT] -> bf16 MFMA B-fragment order ----------
// Wp element ((t*4+kk)*64 + l)*8 + i  <-  W[kk*32 + (l>>4)*8 + i][t*16 + (l&15)]
// so in the GEMM, lane l's B-frag for (tile t, K-step kk) is one contiguous 16B read.

template <int DOUT>
__global__ __launch_bounds__(256)
void k_pack_w(const float* __restrict__ W, u16* __restrict__ Wp) {
    int gid = blockIdx.x * 256 + threadIdx.x;
    if (gid >= DOUT * 128) return;
    int i  = gid & 7;
    int l  = (gid >> 3) & 63;
    int kk = (gid >> 9) & 3;
    int t  = gid >> 11;
    int k = kk * 32 + ((l >> 4) << 3) + i;
    int c = t * 16 + (l & 15);
    Wp[gid] = f2bf(W[k * DOUT + c]);
}

// ---------------- GEMM: G = (H @ W) * dinv[row], bf16 MFMA, LDS-free -------------
// H: bf16 [n][128]; Wp: packed bf16; G: fp32 [n][DOUT].
// Block = 4 waves; wave w owns rows r0+w*16 .. +15, all DOUT cols (NT 16x16 tiles).
// A-frag (16x16x32): lane l holds A[l&15][(l>>4)*8 + i]  -> 16B global read per K-step.
// D: col=l&15, row=(l>>4)*4+reg  (guide §3, m89-verified).

template <int DOUT>
__global__ __launch_bounds__(256)
void k_gemm_mfma(const u16* __restrict__ Hb, const u16* __restrict__ Wp,
                 const float* __restrict__ dinv, float* __restrict__ G, int n) {
    constexpr int NT = DOUT / 16;
    int tid = threadIdx.x;
    int w = tid >> 6, l = tid & 63;
    int r0 = blockIdx.x * 64 + w * 16;
    int arow = r0 + (l & 15);
    bool avalid = arow < n;
    const s16x8* Arow = (const s16x8*)(Hb + (size_t)arow * 128);  // 16 x 16B units/row
    const s16x8* Wp8 = (const s16x8*)Wp;
    const s16x8 zero = {0, 0, 0, 0, 0, 0, 0, 0};

    f32x4 acc[NT];
#pragma unroll
    for (int t = 0; t < NT; t++) acc[t] = {0.f, 0.f, 0.f, 0.f};

#pragma unroll
    for (int kk = 0; kk < 4; kk++) {                 // K = 128 = 4 x 32
        s16x8 a = avalid ? Arow[kk * 4 + (l >> 4)] : zero;
#pragma unroll
        for (int t = 0; t < NT; t++) {
            s16x8 b = Wp8[(t * 4 + kk) * 64 + l];
            acc[t] = __builtin_amdgcn_mfma_f32_16x16x32_bf16(a, b, acc[t], 0, 0, 0);
        }
    }

    int col = l & 15;
#pragma unroll
    for (int r = 0; r < 4; r++) {
        int gr = r0 + (l >> 4) * 4 + r;
        if (gr < n) {
            float di = dinv[gr];
#pragma unroll
            for (int t = 0; t < NT; t++)
                G[(size_t)gr * DOUT + t * 16 + col] = acc[t][r] * di;
        }
    }
}

// ---------------- aggregation (gather) ----------------
// one wave per node; unroll-by-4 for MLP (round-4: fixed the latency bound).
// Output is bf16 (packed pair per lane) -> feeds next layer's MFMA GEMM directly.

__global__ __launch_bounds__(256)
void k_agg_relu(const float* __restrict__ G, const int* __restrict__ offs,
                const int* __restrict__ deg, const int* __restrict__ srcs,
                const float* __restrict__ dinv, const float* __restrict__ bias,
                unsigned* __restrict__ out, int n) {
    int wid = (blockIdx.x * 256 + threadIdx.x) >> 6;
    int lane = threadIdx.x & 63;
    if (wid >= n) return;
    const float2* G2 = (const float2*)G;
    float2 a0 = G2[(size_t)wid * 64 + lane];   // self-loop contribution
    float2 a1 = make_float2(0.f, 0.f);
    float2 a2 = make_float2(0.f, 0.f);
    float2 a3 = make_float2(0.f, 0.f);
    int start = offs[wid];
    int cnt = deg[wid];
    int j = 0;
    for (; j + 4 <= cnt; j += 4) {
        int s0 = srcs[start + j + 0];
        int s1 = srcs[start + j + 1];
        int s2 = srcs[start + j + 2];
        int s3 = srcs[start + j + 3];
        float2 v0 = G2[(size_t)s0 * 64 + lane];
        float2 v1 = G2[(size_t)s1 * 64 + lane];
        float2 v2 = G2[(size_t)s2 * 64 + lane];
        float2 v3 = G2[(size_t)s3 * 64 + lane];
        a0.x += v0.x; a0.y += v0.y;
        a1.x += v1.x; a1.y += v1.y;
        a2.x += v2.x; a2.y += v2.y;
        a3.x += v3.x; a3.y += v3.y;
    }
    for (; j < cnt; j++) {
        int s = srcs[start + j];
        float2 v = G2[(size_t)s * 64 + lane];
        a0.x += v.x; a0.y += v.y;
    }
    float2 acc;
    acc.x = (a0.x + a1.x) + (a2.x + a3.x);
    acc.y = (a0.y + a1.y) + (a2.y + a3.y);
    float di = dinv[wid];
    float2 bb = ((const float2*)bias)[lane];
    float rx = fmaxf(fmaf(acc.x, di, bb.x), 0.f);
    float ry = fmaxf(fmaf(acc.y, di, bb.y), 0.f);
    out[(size_t)wid * 64 + lane] = (unsigned)f2bf(rx) | ((unsigned)f2bf(ry) << 16);
}

// final layer: D=64, one lane per feature, fused log_softmax (fp32 in/out)
__global__ __launch_bounds__(256)
void k_agg_softmax(const float* __restrict__ G, const int* __restrict__ offs,
                   const int* __restrict__ deg, const int* __restrict__ srcs,
                   const float* __restrict__ dinv, const float* __restrict__ bias,
                   float* __restrict__ out, int n) {
    int wid = (blockIdx.x * 256 + threadIdx.x) >> 6;
    int lane = threadIdx.x & 63;
    if (wid >= n) return;
    float a0 = G[(size_t)wid * 64 + lane];     // self-loop
    float a1 = 0.f, a2 = 0.f, a3 = 0.f;
    int start = offs[wid];
    int cnt = deg[wid];
    int j = 0;
    for (; j + 4 <= cnt; j += 4) {
        int s0 = srcs[start + j + 0];
        int s1 = srcs[start + j + 1];
        int s2 = srcs[start + j + 2];
        int s3 = srcs[start + j + 3];
        a0 += G[(size_t)s0 * 64 + lane];
        a1 += G[(size_t)s1 * 64 + lane];
        a2 += G[(size_t)s2 * 64 + lane];
        a3 += G[(size_t)s3 * 64 + lane];
    }
    for (; j < cnt; j++) {
        int s = srcs[start + j];
        a0 += G[(size_t)s * 64 + lane];
    }
    float acc = (a0 + a1) + (a2 + a3);
    float t = fmaf(acc, dinv[wid], bias[lane]);
    float m = t;
    for (int off = 32; off; off >>= 1) m = fmaxf(m, __shfl_xor(m, off, 64));
    float e = expf(t - m);
    float ssum = e;
    for (int off = 32; off; off >>= 1) ssum += __shfl_xor(ssum, off, 64);
    out[(size_t)wid * 64 + lane] = t - m - logf(ssum);
}

// ---------------- launch ----------------

extern "C" void kernel_launch(void* const* d_in, const int* in_sizes, int n_in,
                              void* d_out, int out_size, void* d_ws, size_t ws_size,
                              hipStream_t stream) {
    const float* x  = (const float*)d_in[0];
    const int*   ei = (const int*)d_in[1];
    const int*   row = ei;             // edge_index[0]: source
    const int*   col = ei + NE;        // edge_index[1]: destination
    const float* W1 = (const float*)d_in[2];
    const float* b1 = (const float*)d_in[3];
    const float* W2 = (const float*)d_in[4];
    const float* b2 = (const float*)d_in[5];
    const float* W3 = (const float*)d_in[6];
    const float* b3 = (const float*)d_in[7];
    float* outp = (float*)d_out;

    char* ws = (char*)d_ws;
    size_t off = 0;
    auto alloc = [&](size_t bytes) -> void* {
        void* p = (void*)(ws + off);
        off += (bytes + 255) & ~(size_t)255;
        return p;
    };
    float* dinv  = (float*)alloc((size_t)NN * 4);
    float* bufA  = (float*)alloc((size_t)NN * 128 * 4);   // fp32 G
    u16*   bufB  = (u16*)alloc((size_t)NN * 128 * 2);     // bf16 H (layers 2,3)
    u16*   xb    = (u16*)alloc((size_t)NN * 128 * 2);     // bf16 x
    int*   deg   = (int*)alloc((size_t)NN * 4);
    int*   offs  = (int*)alloc((size_t)NN * 4);
    int*   cursor= (int*)alloc((size_t)NN * 4);
    int*   bsums = (int*)alloc(1024 * 4);
    int*   srcs  = (int*)alloc((size_t)NE * 4);
    u16*   wp1   = (u16*)alloc(128 * 128 * 2);
    u16*   wp2   = (u16*)alloc(128 * 128 * 2);
    u16*   wp3   = (u16*)alloc(128 * 64 * 2);

    int nbN = (NN + 255) / 256;   // 391
    int nbE = (NE + 255) / 256;

    k_init_deg <<<nbN, 256, 0, stream>>>(deg, NN);
    k_deg_count<<<nbE, 256, 0, stream>>>(col, deg, NE);
    k_dinv     <<<nbN, 256, 0, stream>>>(deg, dinv, NN);
    k_scan1    <<<nbN, 256, 0, stream>>>(deg, offs, bsums, NN);
    k_scan2    <<<1,   512, 0, stream>>>(bsums, nbN);
    k_scan3    <<<nbN, 256, 0, stream>>>(offs, bsums, cursor, NN);
    k_fill     <<<nbE, 256, 0, stream>>>(row, col, cursor, srcs, NE);

    int n8 = NN * 128 / 8;                         // 1.6M
    k_cvt_bf16 <<<(n8 + 255) / 256, 256, 0, stream>>>(x, xb, n8);
    k_pack_w<128><<<64, 256, 0, stream>>>(W1, wp1);
    k_pack_w<128><<<64, 256, 0, stream>>>(W2, wp2);
    k_pack_w<64> <<<32, 256, 0, stream>>>(W3, wp3);

    int gb = (NN + 63) / 64;              // 1563
    int ab = (NN * 64 + 255) / 256;       // 25000 (wave per node)

    // layer 1: xb -> bufA(G) -> bufB(bf16 h1)
    k_gemm_mfma<128><<<gb, 256, 0, stream>>>(xb, wp1, dinv, bufA, NN);
    k_agg_relu <<<ab, 256, 0, stream>>>(bufA, offs, deg, srcs, dinv, b1, (unsigned*)bufB, NN);
    // layer 2: bufB -> bufA(G) -> bufB(bf16 h2)
    k_gemm_mfma<128><<<gb, 256, 0, stream>>>(bufB, wp2, dinv, bufA, NN);
    k_agg_relu <<<ab, 256, 0, stream>>>(bufA, offs, deg, srcs, dinv, b2, (unsigned*)bufB, NN);
    // layer 3: bufB -> bufA(G, 64-wide) -> out (log_softmax)
    k_gemm_mfma<64> <<<gb, 256, 0, stream>>>(bufB, wp3, dinv, bufA, NN);
    k_agg_softmax<<<ab, 256, 0, stream>>>(bufA, offs, deg, srcs, dinv, b3, outp, NN);
}

// Round 8
// 359.178 us; speedup vs baseline: 1.4854x; 1.0760x over previous
//
#include <hip/hip_runtime.h>

#define NN 100000
#define NE 600000

typedef unsigned short u16;
typedef float f32x4 __attribute__((ext_vector_type(4)));
typedef short s16x8 __attribute__((ext_vector_type(8)));
typedef u16 u16x8 __attribute__((ext_vector_type(8)));

__device__ inline u16 f2bf(float f) {            // fp32 -> bf16 RNE
    unsigned u = __float_as_uint(f);
    return (u16)((u + 0x7FFFu + ((u >> 16) & 1u)) >> 16);
}
__device__ inline float bflo(unsigned u) { return __uint_as_float(u << 16); }
__device__ inline float bfhi(unsigned u) { return __uint_as_float(u & 0xFFFF0000u); }

// ---------------- degree / CSR build ----------------

__global__ void k_init_deg(int* __restrict__ deg, int n) {
    int i = blockIdx.x * 256 + threadIdx.x;
    if (i < n) deg[i] = 0;
}

__global__ void k_deg_count(const int* __restrict__ col, int* __restrict__ deg, int E) {
    int e = blockIdx.x * 256 + threadIdx.x;
    if (e < E) atomicAdd(&deg[col[e]], 1);
}

__global__ void k_dinv(const int* __restrict__ deg, float* __restrict__ dinv, int n) {
    int i = blockIdx.x * 256 + threadIdx.x;
    if (i < n) dinv[i] = rsqrtf((float)(deg[i] + 1));   // +1: self-loop
}

__global__ void k_scan1(const int* __restrict__ deg, int* __restrict__ offs,
                        int* __restrict__ bsums, int n) {
    __shared__ int s[256];
    int t = threadIdx.x;
    int i = blockIdx.x * 256 + t;
    int v = (i < n) ? deg[i] : 0;
    s[t] = v;
    __syncthreads();
    for (int off = 1; off < 256; off <<= 1) {
        int x = (t >= off) ? s[t - off] : 0;
        __syncthreads();
        s[t] += x;
        __syncthreads();
    }
    if (i < n) offs[i] = s[t] - v;
    if (t == 255) bsums[blockIdx.x] = s[255];
}

__global__ void k_scan2(int* __restrict__ bsums, int nb) {
    __shared__ int s[512];
    int t = threadIdx.x;
    int v = (t < nb) ? bsums[t] : 0;
    s[t] = v;
    __syncthreads();
    for (int off = 1; off < 512; off <<= 1) {
        int x = (t >= off) ? s[t - off] : 0;
        __syncthreads();
        s[t] += x;
        __syncthreads();
    }
    if (t < nb) bsums[t] = s[t] - v;
}

__global__ void k_scan3(int* __restrict__ offs, const int* __restrict__ bsums,
                        int* __restrict__ cursor, int n) {
    int i = blockIdx.x * 256 + threadIdx.x;
    if (i < n) {
        int o = offs[i] + bsums[i >> 8];
        offs[i] = o;
        cursor[i] = o;
    }
}

__global__ void k_fill(const int* __restrict__ row, const int* __restrict__ col,
                       int* __restrict__ cursor, int* __restrict__ srcs, int E) {
    int e = blockIdx.x * 256 + threadIdx.x;
    if (e < E) {
        int p = atomicAdd(&cursor[col[e]], 1);
        srcs[p] = row[e];
    }
}

// ---------------- fp32 -> bf16 conversion (x only; 8 elems/thread) ----------------

__global__ __launch_bounds__(256)
void k_cvt_bf16(const float* __restrict__ in, u16* __restrict__ out, int n8) {
    int i = blockIdx.x * 256 + threadIdx.x;
    if (i >= n8) return;
    const float4* p = (const float4*)in;
    float4 v0 = p[i * 2], v1 = p[i * 2 + 1];
    u16x8 r;
    r[0] = f2bf(v0.x); r[1] = f2bf(v0.y); r[2] = f2bf(v0.z); r[3] = f2bf(v0.w);
    r[4] = f2bf(v1.x); r[5] = f2bf(v1.y); r[6] = f2bf(v1.z); r[7] = f2bf(v1.w);
    ((u16x8*)out)[i] = r;
}

// ---------------- W pack: fp32 [128][DOUT] -> bf16 MFMA B-fragment order ----------
// Wp element ((t*4+kk)*64 + l)*8 + i  <-  W[kk*32 + (l>>4)*8 + i][t*16 + (l&15)]

template <int DOUT>
__global__ __launch_bounds__(256)
void k_pack_w(const float* __restrict__ W, u16* __restrict__ Wp) {
    int gid = blockIdx.x * 256 + threadIdx.x;
    if (gid >= DOUT * 128) return;
    int i  = gid & 7;
    int l  = (gid >> 3) & 63;
    int kk = (gid >> 9) & 3;
    int t  = gid >> 11;
    int k = kk * 32 + ((l >> 4) << 3) + i;
    int c = t * 16 + (l & 15);
    Wp[gid] = f2bf(W[k * DOUT + c]);
}

// ---------------- GEMM: G = (H @ W) * dinv[row], bf16 MFMA, LDS-free -------------
// H: bf16 [n][128]; Wp: packed bf16; G: bf16 [n][DOUT] (OB16) or fp32.
// Block = 4 waves; wave w owns rows r0+w*16 .. +15, all DOUT cols (NT 16x16 tiles).
// A-frag (16x16x32): lane l holds A[l&15][(l>>4)*8 + i]  -> 16B global read per K-step.
// D: col=l&15, row=(l>>4)*4+reg  (guide §3, m89-verified).

template <int DOUT, bool OB16>
__global__ __launch_bounds__(256)
void k_gemm_mfma(const u16* __restrict__ Hb, const u16* __restrict__ Wp,
                 const float* __restrict__ dinv, void* __restrict__ Gout, int n) {
    constexpr int NT = DOUT / 16;
    int tid = threadIdx.x;
    int w = tid >> 6, l = tid & 63;
    int r0 = blockIdx.x * 64 + w * 16;
    int arow = r0 + (l & 15);
    bool avalid = arow < n;
    const s16x8* Arow = (const s16x8*)(Hb + (size_t)arow * 128);
    const s16x8* Wp8 = (const s16x8*)Wp;
    const s16x8 zero = {0, 0, 0, 0, 0, 0, 0, 0};

    f32x4 acc[NT];
#pragma unroll
    for (int t = 0; t < NT; t++) acc[t] = {0.f, 0.f, 0.f, 0.f};

#pragma unroll
    for (int kk = 0; kk < 4; kk++) {                 // K = 128 = 4 x 32
        s16x8 a = avalid ? Arow[kk * 4 + (l >> 4)] : zero;
#pragma unroll
        for (int t = 0; t < NT; t++) {
            s16x8 b = Wp8[(t * 4 + kk) * 64 + l];
            acc[t] = __builtin_amdgcn_mfma_f32_16x16x32_bf16(a, b, acc[t], 0, 0, 0);
        }
    }

    int col = l & 15;
#pragma unroll
    for (int r = 0; r < 4; r++) {
        int gr = r0 + (l >> 4) * 4 + r;
        if (gr < n) {
            float di = dinv[gr];
#pragma unroll
            for (int t = 0; t < NT; t++) {
                float v = acc[t][r] * di;
                if (OB16)
                    ((u16*)Gout)[(size_t)gr * DOUT + t * 16 + col] = f2bf(v);
                else
                    ((float*)Gout)[(size_t)gr * DOUT + t * 16 + col] = v;
            }
        }
    }
}

// ---------------- aggregation (gather) ----------------
// one wave per node; unroll-by-4 for MLP. G is bf16 [n][128]: lane reads one u32
// (2 dims, 4B/lane -> 256B/row coalesced), accumulates fp32, emits packed bf16.

__global__ __launch_bounds__(256)
void k_agg_relu(const unsigned* __restrict__ G, const int* __restrict__ offs,
                const int* __restrict__ deg, const int* __restrict__ srcs,
                const float* __restrict__ dinv, const float* __restrict__ bias,
                unsigned* __restrict__ out, int n) {
    int wid = (blockIdx.x * 256 + threadIdx.x) >> 6;
    int lane = threadIdx.x & 63;
    if (wid >= n) return;
    unsigned us = G[(size_t)wid * 64 + lane];      // self-loop contribution
    float2 a0 = make_float2(bflo(us), bfhi(us));
    float2 a1 = make_float2(0.f, 0.f);
    float2 a2 = make_float2(0.f, 0.f);
    float2 a3 = make_float2(0.f, 0.f);
    int start = offs[wid];
    int cnt = deg[wid];
    int j = 0;
    for (; j + 4 <= cnt; j += 4) {
        int s0 = srcs[start + j + 0];
        int s1 = srcs[start + j + 1];
        int s2 = srcs[start + j + 2];
        int s3 = srcs[start + j + 3];
        unsigned u0 = G[(size_t)s0 * 64 + lane];
        unsigned u1 = G[(size_t)s1 * 64 + lane];
        unsigned u2 = G[(size_t)s2 * 64 + lane];
        unsigned u3 = G[(size_t)s3 * 64 + lane];
        a0.x += bflo(u0); a0.y += bfhi(u0);
        a1.x += bflo(u1); a1.y += bfhi(u1);
        a2.x += bflo(u2); a2.y += bfhi(u2);
        a3.x += bflo(u3); a3.y += bfhi(u3);
    }
    for (; j < cnt; j++) {
        int s = srcs[start + j];
        unsigned u = G[(size_t)s * 64 + lane];
        a0.x += bflo(u); a0.y += bfhi(u);
    }
    float2 acc;
    acc.x = (a0.x + a1.x) + (a2.x + a3.x);
    acc.y = (a0.y + a1.y) + (a2.y + a3.y);
    float di = dinv[wid];
    float2 bb = ((const float2*)bias)[lane];
    float rx = fmaxf(fmaf(acc.x, di, bb.x), 0.f);
    float ry = fmaxf(fmaf(acc.y, di, bb.y), 0.f);
    out[(size_t)wid * 64 + lane] = (unsigned)f2bf(rx) | ((unsigned)f2bf(ry) << 16);
}

// final layer: D=64, one lane per feature, fused log_softmax (fp32 in/out)
__global__ __launch_bounds__(256)
void k_agg_softmax(const float* __restrict__ G, const int* __restrict__ offs,
                   const int* __restrict__ deg, const int* __restrict__ srcs,
                   const float* __restrict__ dinv, const float* __restrict__ bias,
                   float* __restrict__ out, int n) {
    int wid = (blockIdx.x * 256 + threadIdx.x) >> 6;
    int lane = threadIdx.x & 63;
    if (wid >= n) return;
    float a0 = G[(size_t)wid * 64 + lane];     // self-loop
    float a1 = 0.f, a2 = 0.f, a3 = 0.f;
    int start = offs[wid];
    int cnt = deg[wid];
    int j = 0;
    for (; j + 4 <= cnt; j += 4) {
        int s0 = srcs[start + j + 0];
        int s1 = srcs[start + j + 1];
        int s2 = srcs[start + j + 2];
        int s3 = srcs[start + j + 3];
        a0 += G[(size_t)s0 * 64 + lane];
        a1 += G[(size_t)s1 * 64 + lane];
        a2 += G[(size_t)s2 * 64 + lane];
        a3 += G[(size_t)s3 * 64 + lane];
    }
    for (; j < cnt; j++) {
        int s = srcs[start + j];
        a0 += G[(size_t)s * 64 + lane];
    }
    float acc = (a0 + a1) + (a2 + a3);
    float t = fmaf(acc, dinv[wid], bias[lane]);
    float m = t;
    for (int off = 32; off; off >>= 1) m = fmaxf(m, __shfl_xor(m, off, 64));
    float e = expf(t - m);
    float ssum = e;
    for (int off = 32; off; off >>= 1) ssum += __shfl_xor(ssum, off, 64);
    out[(size_t)wid * 64 + lane] = t - m - logf(ssum);
}

// ---------------- launch ----------------

extern "C" void kernel_launch(void* const* d_in, const int* in_sizes, int n_in,
                              void* d_out, int out_size, void* d_ws, size_t ws_size,
                              hipStream_t stream) {
    const float* x  = (const float*)d_in[0];
    const int*   ei = (const int*)d_in[1];
    const int*   row = ei;             // edge_index[0]: source
    const int*   col = ei + NE;        // edge_index[1]: destination
    const float* W1 = (const float*)d_in[2];
    const float* b1 = (const float*)d_in[3];
    const float* W2 = (const float*)d_in[4];
    const float* b2 = (const float*)d_in[5];
    const float* W3 = (const float*)d_in[6];
    const float* b3 = (const float*)d_in[7];
    float* outp = (float*)d_out;

    char* ws = (char*)d_ws;
    size_t off = 0;
    auto alloc = [&](size_t bytes) -> void* {
        void* p = (void*)(ws + off);
        off += (bytes + 255) & ~(size_t)255;
        return p;
    };
    float* dinv  = (float*)alloc((size_t)NN * 4);
    float* bufA  = (float*)alloc((size_t)NN * 128 * 4);   // bf16 G (L1,2) / fp32 G (L3)
    u16*   bufB  = (u16*)alloc((size_t)NN * 128 * 2);     // bf16 H (layers 2,3)
    u16*   xb    = (u16*)alloc((size_t)NN * 128 * 2);     // bf16 x
    int*   deg   = (int*)alloc((size_t)NN * 4);
    int*   offs  = (int*)alloc((size_t)NN * 4);
    int*   cursor= (int*)alloc((size_t)NN * 4);
    int*   bsums = (int*)alloc(1024 * 4);
    int*   srcs  = (int*)alloc((size_t)NE * 4);
    u16*   wp1   = (u16*)alloc(128 * 128 * 2);
    u16*   wp2   = (u16*)alloc(128 * 128 * 2);
    u16*   wp3   = (u16*)alloc(128 * 64 * 2);

    int nbN = (NN + 255) / 256;   // 391
    int nbE = (NE + 255) / 256;

    k_init_deg <<<nbN, 256, 0, stream>>>(deg, NN);
    k_deg_count<<<nbE, 256, 0, stream>>>(col, deg, NE);
    k_dinv     <<<nbN, 256, 0, stream>>>(deg, dinv, NN);
    k_scan1    <<<nbN, 256, 0, stream>>>(deg, offs, bsums, NN);
    k_scan2    <<<1,   512, 0, stream>>>(bsums, nbN);
    k_scan3    <<<nbN, 256, 0, stream>>>(offs, bsums, cursor, NN);
    k_fill     <<<nbE, 256, 0, stream>>>(row, col, cursor, srcs, NE);

    int n8 = NN * 128 / 8;                         // 1.6M
    k_cvt_bf16 <<<(n8 + 255) / 256, 256, 0, stream>>>(x, xb, n8);
    k_pack_w<128><<<64, 256, 0, stream>>>(W1, wp1);
    k_pack_w<128><<<64, 256, 0, stream>>>(W2, wp2);
    k_pack_w<64> <<<32, 256, 0, stream>>>(W3, wp3);

    int gb = (NN + 63) / 64;              // 1563
    int ab = (NN * 64 + 255) / 256;       // 25000 (wave per node)

    // layer 1: xb -> bufA(bf16 G) -> bufB(bf16 h1)
    k_gemm_mfma<128, true><<<gb, 256, 0, stream>>>(xb, wp1, dinv, bufA, NN);
    k_agg_relu <<<ab, 256, 0, stream>>>((unsigned*)bufA, offs, deg, srcs, dinv, b1, (unsigned*)bufB, NN);
    // layer 2: bufB -> bufA(bf16 G) -> bufB(bf16 h2)
    k_gemm_mfma<128, true><<<gb, 256, 0, stream>>>(bufB, wp2, dinv, bufA, NN);
    k_agg_relu <<<ab, 256, 0, stream>>>((unsigned*)bufA, offs, deg, srcs, dinv, b2, (unsigned*)bufB, NN);
    // layer 3: bufB -> bufA(fp32 G, 64-wide) -> out (log_softmax)
    k_gemm_mfma<64, false><<<gb, 256, 0, stream>>>(bufB, wp3, dinv, bufA, NN);
    k_agg_softmax<<<ab, 256, 0, stream>>>(bufA, offs, deg, srcs, dinv, b3, outp, NN);
}

// Round 9
// 323.457 us; speedup vs baseline: 1.6495x; 1.1104x over previous
//
#include <hip/hip_runtime.h>

#define NN 100000
#define NE 600000

typedef unsigned short u16;
typedef float f32x4 __attribute__((ext_vector_type(4)));
typedef short s16x8 __attribute__((ext_vector_type(8)));
typedef u16 u16x8 __attribute__((ext_vector_type(8)));

__device__ inline u16 f2bf(float f) {            // fp32 -> bf16 RNE
    unsigned u = __float_as_uint(f);
    return (u16)((u + 0x7FFFu + ((u >> 16) & 1u)) >> 16);
}
__device__ inline float bflo(unsigned u) { return __uint_as_float(u << 16); }
__device__ inline float bfhi(unsigned u) { return __uint_as_float(u & 0xFFFF0000u); }
__device__ inline unsigned pk(float a, float b) {
    return (unsigned)f2bf(a) | ((unsigned)f2bf(b) << 16);
}

// ---------------- degree / CSR build ----------------

__global__ void k_init_deg(int* __restrict__ deg, int n) {
    int i = blockIdx.x * 256 + threadIdx.x;
    if (i < n) deg[i] = 0;
}

__global__ void k_deg_count(const int* __restrict__ col, int* __restrict__ deg, int E) {
    int e = blockIdx.x * 256 + threadIdx.x;
    if (e < E) atomicAdd(&deg[col[e]], 1);
}

__global__ void k_dinv(const int* __restrict__ deg, float* __restrict__ dinv, int n) {
    int i = blockIdx.x * 256 + threadIdx.x;
    if (i < n) dinv[i] = rsqrtf((float)(deg[i] + 1));   // +1: self-loop
}

__global__ void k_scan1(const int* __restrict__ deg, int* __restrict__ offs,
                        int* __restrict__ bsums, int n) {
    __shared__ int s[256];
    int t = threadIdx.x;
    int i = blockIdx.x * 256 + t;
    int v = (i < n) ? deg[i] : 0;
    s[t] = v;
    __syncthreads();
    for (int off = 1; off < 256; off <<= 1) {
        int x = (t >= off) ? s[t - off] : 0;
        __syncthreads();
        s[t] += x;
        __syncthreads();
    }
    if (i < n) offs[i] = s[t] - v;
    if (t == 255) bsums[blockIdx.x] = s[255];
}

__global__ void k_scan2(int* __restrict__ bsums, int nb) {
    __shared__ int s[512];
    int t = threadIdx.x;
    int v = (t < nb) ? bsums[t] : 0;
    s[t] = v;
    __syncthreads();
    for (int off = 1; off < 512; off <<= 1) {
        int x = (t >= off) ? s[t - off] : 0;
        __syncthreads();
        s[t] += x;
        __syncthreads();
    }
    if (t < nb) bsums[t] = s[t] - v;
}

__global__ void k_scan3(int* __restrict__ offs, const int* __restrict__ bsums,
                        int* __restrict__ cursor, int n) {
    int i = blockIdx.x * 256 + threadIdx.x;
    if (i < n) {
        int o = offs[i] + bsums[i >> 8];
        offs[i] = o;
        cursor[i] = o;
    }
}

__global__ void k_fill(const int* __restrict__ row, const int* __restrict__ col,
                       int* __restrict__ cursor, int* __restrict__ srcs, int E) {
    int e = blockIdx.x * 256 + threadIdx.x;
    if (e < E) {
        int p = atomicAdd(&cursor[col[e]], 1);
        srcs[p] = row[e];
    }
}

// ---------------- fp32 -> bf16 conversion (x only; 8 elems/thread) ----------------

__global__ __launch_bounds__(256)
void k_cvt_bf16(const float* __restrict__ in, u16* __restrict__ out, int n8) {
    int i = blockIdx.x * 256 + threadIdx.x;
    if (i >= n8) return;
    const float4* p = (const float4*)in;
    float4 v0 = p[i * 2], v1 = p[i * 2 + 1];
    u16x8 r;
    r[0] = f2bf(v0.x); r[1] = f2bf(v0.y); r[2] = f2bf(v0.z); r[3] = f2bf(v0.w);
    r[4] = f2bf(v1.x); r[5] = f2bf(v1.y); r[6] = f2bf(v1.z); r[7] = f2bf(v1.w);
    ((u16x8*)out)[i] = r;
}

// ---------------- W pack: fp32 [128][DOUT] -> bf16 MFMA B-fragment order ----------
// Wp element ((t*4+kk)*64 + l)*8 + i  <-  W[kk*32 + (l>>4)*8 + i][t*16 + (l&15)]

template <int DOUT>
__global__ __launch_bounds__(256)
void k_pack_w(const float* __restrict__ W, u16* __restrict__ Wp) {
    int gid = blockIdx.x * 256 + threadIdx.x;
    if (gid >= DOUT * 128) return;
    int i  = gid & 7;
    int l  = (gid >> 3) & 63;
    int kk = (gid >> 9) & 3;
    int t  = gid >> 11;
    int k = kk * 32 + ((l >> 4) << 3) + i;
    int c = t * 16 + (l & 15);
    Wp[gid] = f2bf(W[k * DOUT + c]);
}

// ---------------- GEMM: G = (H @ W) * dinv[row], bf16 MFMA, LDS-free -------------
// H: bf16 [n][128]; Wp: packed bf16; G: bf16 [n][DOUT] (OB16) or fp32.
// Block = 4 waves; wave w owns rows r0+w*16 .. +15, all DOUT cols (NT 16x16 tiles).
// A-frag (16x16x32): lane l holds A[l&15][(l>>4)*8 + i]  -> 16B global read per K-step.
// D: col=l&15, row=(l>>4)*4+reg  (guide §3, m89-verified).

template <int DOUT, bool OB16>
__global__ __launch_bounds__(256)
void k_gemm_mfma(const u16* __restrict__ Hb, const u16* __restrict__ Wp,
                 const float* __restrict__ dinv, void* __restrict__ Gout, int n) {
    constexpr int NT = DOUT / 16;
    int tid = threadIdx.x;
    int w = tid >> 6, l = tid & 63;
    int r0 = blockIdx.x * 64 + w * 16;
    int arow = r0 + (l & 15);
    bool avalid = arow < n;
    const s16x8* Arow = (const s16x8*)(Hb + (size_t)arow * 128);
    const s16x8* Wp8 = (const s16x8*)Wp;
    const s16x8 zero = {0, 0, 0, 0, 0, 0, 0, 0};

    f32x4 acc[NT];
#pragma unroll
    for (int t = 0; t < NT; t++) acc[t] = {0.f, 0.f, 0.f, 0.f};

#pragma unroll
    for (int kk = 0; kk < 4; kk++) {                 // K = 128 = 4 x 32
        s16x8 a = avalid ? Arow[kk * 4 + (l >> 4)] : zero;
#pragma unroll
        for (int t = 0; t < NT; t++) {
            s16x8 b = Wp8[(t * 4 + kk) * 64 + l];
            acc[t] = __builtin_amdgcn_mfma_f32_16x16x32_bf16(a, b, acc[t], 0, 0, 0);
        }
    }

    int col = l & 15;
#pragma unroll
    for (int r = 0; r < 4; r++) {
        int gr = r0 + (l >> 4) * 4 + r;
        if (gr < n) {
            float di = dinv[gr];
#pragma unroll
            for (int t = 0; t < NT; t++) {
                float v = acc[t][r] * di;
                if (OB16)
                    ((u16*)Gout)[(size_t)gr * DOUT + t * 16 + col] = f2bf(v);
                else
                    ((float*)Gout)[(size_t)gr * DOUT + t * 16 + col] = v;
            }
        }
    }
}

// ---------------- aggregation (gather) ----------------
// 2 nodes per wave (32-lane half-waves). G bf16 [n][128] = [n][32] uint2:
// lane covers 4 features (8B/lane) -> each load instr moves 2 rows (512B/wave).
// unroll-by-4 independent gathers for MLP; fp32 accumulate; bf16 packed output.

__global__ __launch_bounds__(256)
void k_agg_relu(const uint2* __restrict__ G, const int* __restrict__ offs,
                const int* __restrict__ deg, const int* __restrict__ srcs,
                const float* __restrict__ dinv, const float* __restrict__ bias,
                uint2* __restrict__ out, int n) {
    int t = blockIdx.x * 256 + threadIdx.x;
    int wv = t >> 6;
    int lane = t & 63;
    int hl = lane & 31;                 // lane within half-wave
    int node = wv * 2 + (lane >> 5);    // 2 nodes per wave
    if (node >= n) return;

    uint2 us = G[(size_t)node * 32 + hl];          // self-loop
    float4 a0 = make_float4(bflo(us.x), bfhi(us.x), bflo(us.y), bfhi(us.y));
    float4 a1 = make_float4(0.f, 0.f, 0.f, 0.f);
    float4 a2 = make_float4(0.f, 0.f, 0.f, 0.f);
    float4 a3 = make_float4(0.f, 0.f, 0.f, 0.f);
    int start = offs[node];
    int cnt = deg[node];
    int j = 0;
    for (; j + 4 <= cnt; j += 4) {
        int s0 = srcs[start + j + 0];
        int s1 = srcs[start + j + 1];
        int s2 = srcs[start + j + 2];
        int s3 = srcs[start + j + 3];
        uint2 u0 = G[(size_t)s0 * 32 + hl];
        uint2 u1 = G[(size_t)s1 * 32 + hl];
        uint2 u2 = G[(size_t)s2 * 32 + hl];
        uint2 u3 = G[(size_t)s3 * 32 + hl];
        a0.x += bflo(u0.x); a0.y += bfhi(u0.x); a0.z += bflo(u0.y); a0.w += bfhi(u0.y);
        a1.x += bflo(u1.x); a1.y += bfhi(u1.x); a1.z += bflo(u1.y); a1.w += bfhi(u1.y);
        a2.x += bflo(u2.x); a2.y += bfhi(u2.x); a2.z += bflo(u2.y); a2.w += bfhi(u2.y);
        a3.x += bflo(u3.x); a3.y += bfhi(u3.x); a3.z += bflo(u3.y); a3.w += bfhi(u3.y);
    }
    for (; j < cnt; j++) {
        int s = srcs[start + j];
        uint2 u = G[(size_t)s * 32 + hl];
        a0.x += bflo(u.x); a0.y += bfhi(u.x); a0.z += bflo(u.y); a0.w += bfhi(u.y);
    }
    float4 acc;
    acc.x = (a0.x + a1.x) + (a2.x + a3.x);
    acc.y = (a0.y + a1.y) + (a2.y + a3.y);
    acc.z = (a0.z + a1.z) + (a2.z + a3.z);
    acc.w = (a0.w + a1.w) + (a2.w + a3.w);
    float di = dinv[node];
    float4 bb = ((const float4*)bias)[hl];
    float r0 = fmaxf(fmaf(acc.x, di, bb.x), 0.f);
    float r1 = fmaxf(fmaf(acc.y, di, bb.y), 0.f);
    float r2 = fmaxf(fmaf(acc.z, di, bb.z), 0.f);
    float r3 = fmaxf(fmaf(acc.w, di, bb.w), 0.f);
    out[(size_t)node * 32 + hl] = make_uint2(pk(r0, r1), pk(r2, r3));
}

// final layer: G bf16 [n][64] = [n][32] u32; 2 nodes/wave, lane covers 2 features.
// log_softmax reduction: pairwise + 5 shfl_xor within the 32-lane half-wave.
__global__ __launch_bounds__(256)
void k_agg_softmax(const unsigned* __restrict__ G, const int* __restrict__ offs,
                   const int* __restrict__ deg, const int* __restrict__ srcs,
                   const float* __restrict__ dinv, const float* __restrict__ bias,
                   float2* __restrict__ out, int n) {
    int t = blockIdx.x * 256 + threadIdx.x;
    int wv = t >> 6;
    int lane = t & 63;
    int hl = lane & 31;
    int node = wv * 2 + (lane >> 5);
    if (node >= n) return;

    unsigned us = G[(size_t)node * 32 + hl];       // self-loop
    float2 a0 = make_float2(bflo(us), bfhi(us));
    float2 a1 = make_float2(0.f, 0.f);
    float2 a2 = make_float2(0.f, 0.f);
    float2 a3 = make_float2(0.f, 0.f);
    int start = offs[node];
    int cnt = deg[node];
    int j = 0;
    for (; j + 4 <= cnt; j += 4) {
        int s0 = srcs[start + j + 0];
        int s1 = srcs[start + j + 1];
        int s2 = srcs[start + j + 2];
        int s3 = srcs[start + j + 3];
        unsigned u0 = G[(size_t)s0 * 32 + hl];
        unsigned u1 = G[(size_t)s1 * 32 + hl];
        unsigned u2 = G[(size_t)s2 * 32 + hl];
        unsigned u3 = G[(size_t)s3 * 32 + hl];
        a0.x += bflo(u0); a0.y += bfhi(u0);
        a1.x += bflo(u1); a1.y += bfhi(u1);
        a2.x += bflo(u2); a2.y += bfhi(u2);
        a3.x += bflo(u3); a3.y += bfhi(u3);
    }
    for (; j < cnt; j++) {
        int s = srcs[start + j];
        unsigned u = G[(size_t)s * 32 + hl];
        a0.x += bflo(u); a0.y += bfhi(u);
    }
    float di = dinv[node];
    float2 bb = ((const float2*)bias)[hl];
    float t0 = fmaf((a0.x + a1.x) + (a2.x + a3.x), di, bb.x);
    float t1 = fmaf((a0.y + a1.y) + (a2.y + a3.y), di, bb.y);
    float m = fmaxf(t0, t1);
#pragma unroll
    for (int off = 1; off < 32; off <<= 1) m = fmaxf(m, __shfl_xor(m, off, 64));
    float e = expf(t0 - m) + expf(t1 - m);
#pragma unroll
    for (int off = 1; off < 32; off <<= 1) e += __shfl_xor(e, off, 64);
    float lse = m + logf(e);
    out[(size_t)node * 32 + hl] = make_float2(t0 - lse, t1 - lse);
}

// ---------------- launch ----------------

extern "C" void kernel_launch(void* const* d_in, const int* in_sizes, int n_in,
                              void* d_out, int out_size, void* d_ws, size_t ws_size,
                              hipStream_t stream) {
    const float* x  = (const float*)d_in[0];
    const int*   ei = (const int*)d_in[1];
    const int*   row = ei;             // edge_index[0]: source
    const int*   col = ei + NE;        // edge_index[1]: destination
    const float* W1 = (const float*)d_in[2];
    const float* b1 = (const float*)d_in[3];
    const float* W2 = (const float*)d_in[4];
    const float* b2 = (const float*)d_in[5];
    const float* W3 = (const float*)d_in[6];
    const float* b3 = (const float*)d_in[7];
    float* outp = (float*)d_out;

    char* ws = (char*)d_ws;
    size_t off = 0;
    auto alloc = [&](size_t bytes) -> void* {
        void* p = (void*)(ws + off);
        off += (bytes + 255) & ~(size_t)255;
        return p;
    };
    float* dinv  = (float*)alloc((size_t)NN * 4);
    float* bufA  = (float*)alloc((size_t)NN * 128 * 4);   // bf16 G (all layers)
    u16*   bufB  = (u16*)alloc((size_t)NN * 128 * 2);     // bf16 H (layers 2,3)
    u16*   xb    = (u16*)alloc((size_t)NN * 128 * 2);     // bf16 x
    int*   deg   = (int*)alloc((size_t)NN * 4);
    int*   offs  = (int*)alloc((size_t)NN * 4);
    int*   cursor= (int*)alloc((size_t)NN * 4);
    int*   bsums = (int*)alloc(1024 * 4);
    int*   srcs  = (int*)alloc((size_t)NE * 4);
    u16*   wp1   = (u16*)alloc(128 * 128 * 2);
    u16*   wp2   = (u16*)alloc(128 * 128 * 2);
    u16*   wp3   = (u16*)alloc(128 * 64 * 2);

    int nbN = (NN + 255) / 256;   // 391
    int nbE = (NE + 255) / 256;

    k_init_deg <<<nbN, 256, 0, stream>>>(deg, NN);
    k_deg_count<<<nbE, 256, 0, stream>>>(col, deg, NE);
    k_dinv     <<<nbN, 256, 0, stream>>>(deg, dinv, NN);
    k_scan1    <<<nbN, 256, 0, stream>>>(deg, offs, bsums, NN);
    k_scan2    <<<1,   512, 0, stream>>>(bsums, nbN);
    k_scan3    <<<nbN, 256, 0, stream>>>(offs, bsums, cursor, NN);
    k_fill     <<<nbE, 256, 0, stream>>>(row, col, cursor, srcs, NE);

    int n8 = NN * 128 / 8;                         // 1.6M
    k_cvt_bf16 <<<(n8 + 255) / 256, 256, 0, stream>>>(x, xb, n8);
    k_pack_w<128><<<64, 256, 0, stream>>>(W1, wp1);
    k_pack_w<128><<<64, 256, 0, stream>>>(W2, wp2);
    k_pack_w<64> <<<32, 256, 0, stream>>>(W3, wp3);

    int gb = (NN + 63) / 64;                 // 1563
    int ab2 = ((NN + 1) / 2 * 64 + 255) / 256;  // 2 nodes/wave -> 12500 blocks

    // layer 1: xb -> bufA(bf16 G) -> bufB(bf16 h1)
    k_gemm_mfma<128, true><<<gb, 256, 0, stream>>>(xb, wp1, dinv, bufA, NN);
    k_agg_relu <<<ab2, 256, 0, stream>>>((uint2*)bufA, offs, deg, srcs, dinv, b1, (uint2*)bufB, NN);
    // layer 2: bufB -> bufA(bf16 G) -> bufB(bf16 h2)
    k_gemm_mfma<128, true><<<gb, 256, 0, stream>>>(bufB, wp2, dinv, bufA, NN);
    k_agg_relu <<<ab2, 256, 0, stream>>>((uint2*)bufA, offs, deg, srcs, dinv, b2, (uint2*)bufB, NN);
    // layer 3: bufB -> bufA(bf16 G, 64-wide) -> out (log_softmax)
    k_gemm_mfma<64, true><<<gb, 256, 0, stream>>>(bufB, wp3, dinv, bufA, NN);
    k_agg_softmax<<<ab2, 256, 0, stream>>>((unsigned*)bufA, offs, deg, srcs, dinv, b3, (float2*)outp, NN);
}

// Round 11
// 307.138 us; speedup vs baseline: 1.7371x; 1.0531x over previous
//
#include <hip/hip_runtime.h>

#define NN 100000
#define NE 600000

typedef unsigned short u16;
typedef float f32x4 __attribute__((ext_vector_type(4)));
typedef short s16x8 __attribute__((ext_vector_type(8)));

__device__ inline u16 f2bf(float f) {            // fp32 -> bf16 RNE
    unsigned u = __float_as_uint(f);
    return (u16)((u + 0x7FFFu + ((u >> 16) & 1u)) >> 16);
}
__device__ inline float bflo(unsigned u) { return __uint_as_float(u << 16); }
__device__ inline float bfhi(unsigned u) { return __uint_as_float(u & 0xFFFF0000u); }
__device__ inline unsigned pk(float a, float b) {
    return (unsigned)f2bf(a) | ((unsigned)f2bf(b) << 16);
}

// ---------------- degree / CSR build ----------------

__global__ void k_init_deg(int* __restrict__ deg, int n) {
    int i = blockIdx.x * 256 + threadIdx.x;
    if (i < n) deg[i] = 0;
}

__global__ void k_deg_count(const int* __restrict__ col, int* __restrict__ deg, int E) {
    int e = blockIdx.x * 256 + threadIdx.x;
    if (e < E) atomicAdd(&deg[col[e]], 1);
}

__global__ void k_dinv(const int* __restrict__ deg, float* __restrict__ dinv, int n) {
    int i = blockIdx.x * 256 + threadIdx.x;
    if (i < n) dinv[i] = rsqrtf((float)(deg[i] + 1));   // +1: self-loop
}

__global__ void k_scan1(const int* __restrict__ deg, int* __restrict__ offs,
                        int* __restrict__ bsums, int n) {
    __shared__ int s[256];
    int t = threadIdx.x;
    int i = blockIdx.x * 256 + t;
    int v = (i < n) ? deg[i] : 0;
    s[t] = v;
    __syncthreads();
    for (int off = 1; off < 256; off <<= 1) {
        int x = (t >= off) ? s[t - off] : 0;
        __syncthreads();
        s[t] += x;
        __syncthreads();
    }
    if (i < n) offs[i] = s[t] - v;
    if (t == 255) bsums[blockIdx.x] = s[255];
}

__global__ void k_scan2(int* __restrict__ bsums, int nb) {
    __shared__ int s[512];
    int t = threadIdx.x;
    int v = (t < nb) ? bsums[t] : 0;
    s[t] = v;
    __syncthreads();
    for (int off = 1; off < 512; off <<= 1) {
        int x = (t >= off) ? s[t - off] : 0;
        __syncthreads();
        s[t] += x;
        __syncthreads();
    }
    if (t < nb) bsums[t] = s[t] - v;
}

__global__ void k_scan3(int* __restrict__ offs, const int* __restrict__ bsums,
                        int* __restrict__ cursor, int n) {
    int i = blockIdx.x * 256 + threadIdx.x;
    if (i < n) {
        int o = offs[i] + bsums[i >> 8];
        offs[i] = o;
        cursor[i] = o;
    }
}

__global__ void k_fill(const int* __restrict__ row, const int* __restrict__ col,
                       int* __restrict__ cursor, int* __restrict__ srcs, int E) {
    int e = blockIdx.x * 256 + threadIdx.x;
    if (e < E) {
        int p = atomicAdd(&cursor[col[e]], 1);
        srcs[p] = row[e];
    }
}

// ---------------- W pack: fp32 [128][DOUT] -> bf16 MFMA B-fragment order ----------
// Wp element ((t*4+kk)*64 + l)*8 + i  <-  W[kk*32 + (l>>4)*8 + i][t*16 + (l&15)]

template <int DOUT>
__global__ __launch_bounds__(256)
void k_pack_w(const float* __restrict__ W, u16* __restrict__ Wp) {
    int gid = blockIdx.x * 256 + threadIdx.x;
    if (gid >= DOUT * 128) return;
    int i  = gid & 7;
    int l  = (gid >> 3) & 63;
    int kk = (gid >> 9) & 3;
    int t  = gid >> 11;
    int k = kk * 32 + ((l >> 4) << 3) + i;
    int c = t * 16 + (l & 15);
    Wp[gid] = f2bf(W[k * DOUT + c]);
}

// ---------------- GEMM: G = (H @ W) * dinv[row], bf16 MFMA, LDS-free -------------
// H: bf16 [n][128] (or fp32 if AF32 — converts in-register, saves the cvt pass);
// Wp: packed bf16; G: bf16 [n][DOUT] (OB16) or fp32.
// Block = 4 waves; wave w owns rows r0+w*16 .. +15, all DOUT cols (NT 16x16 tiles).
// A-frag (16x16x32): lane l holds A[l&15][(l>>4)*8 + i].
// D: col=l&15, row=(l>>4)*4+reg  (guide §3, m89-verified).

template <int DOUT, bool OB16, bool AF32>
__global__ __launch_bounds__(256)
void k_gemm_mfma(const void* __restrict__ Hin, const u16* __restrict__ Wp,
                 const float* __restrict__ dinv, void* __restrict__ Gout, int n) {
    constexpr int NT = DOUT / 16;
    int tid = threadIdx.x;
    int w = tid >> 6, l = tid & 63;
    int r0 = blockIdx.x * 64 + w * 16;
    int arow = r0 + (l & 15);
    bool avalid = arow < n;
    const s16x8* Arow = (const s16x8*)((const u16*)Hin + (size_t)arow * 128);
    const float* Arow32 = (const float*)Hin + (size_t)arow * 128;
    const s16x8* Wp8 = (const s16x8*)Wp;
    const s16x8 zero = {0, 0, 0, 0, 0, 0, 0, 0};

    f32x4 acc[NT];
#pragma unroll
    for (int t = 0; t < NT; t++) acc[t] = {0.f, 0.f, 0.f, 0.f};

#pragma unroll
    for (int kk = 0; kk < 4; kk++) {                 // K = 128 = 4 x 32
        s16x8 a;
        if (AF32) {
            if (avalid) {
                const f32x4* p = (const f32x4*)(Arow32 + kk * 32 + ((l >> 4) << 3));
                f32x4 f0 = p[0], f1 = p[1];
                a[0] = (short)f2bf(f0[0]); a[1] = (short)f2bf(f0[1]);
                a[2] = (short)f2bf(f0[2]); a[3] = (short)f2bf(f0[3]);
                a[4] = (short)f2bf(f1[0]); a[5] = (short)f2bf(f1[1]);
                a[6] = (short)f2bf(f1[2]); a[7] = (short)f2bf(f1[3]);
            } else a = zero;
        } else {
            a = avalid ? Arow[kk * 4 + (l >> 4)] : zero;
        }
#pragma unroll
        for (int t = 0; t < NT; t++) {
            s16x8 b = Wp8[(t * 4 + kk) * 64 + l];
            acc[t] = __builtin_amdgcn_mfma_f32_16x16x32_bf16(a, b, acc[t], 0, 0, 0);
        }
    }

    int col = l & 15;
#pragma unroll
    for (int r = 0; r < 4; r++) {
        int gr = r0 + (l >> 4) * 4 + r;
        if (gr < n) {
            float di = dinv[gr];
#pragma unroll
            for (int t = 0; t < NT; t++) {
                float v = acc[t][r] * di;
                if (OB16)
                    ((u16*)Gout)[(size_t)gr * DOUT + t * 16 + col] = f2bf(v);
                else
                    ((float*)Gout)[(size_t)gr * DOUT + t * 16 + col] = v;
            }
        }
    }
}

// ---------------- aggregation (gather) ----------------
// 4 nodes per wave (16-lane groups), 16B/lane: each load instr moves 4 rows
// (1 KiB/wave). unroll-by-4 independent gathers; fp32 accumulate; bf16 out.

#define ACC8(A, U) \
    A[0] += bflo(U.x); A[1] += bfhi(U.x); A[2] += bflo(U.y); A[3] += bfhi(U.y); \
    A[4] += bflo(U.z); A[5] += bfhi(U.z); A[6] += bflo(U.w); A[7] += bfhi(U.w);

__global__ __launch_bounds__(256)
void k_agg_relu(const uint4* __restrict__ G, const int* __restrict__ offs,
                const int* __restrict__ deg, const int* __restrict__ srcs,
                const float* __restrict__ dinv, const float* __restrict__ bias,
                uint4* __restrict__ out, int n) {
    int t = blockIdx.x * 256 + threadIdx.x;
    int wv = t >> 6;
    int lane = t & 63;
    int hl = lane & 15;                 // lane within 16-lane group
    int node = wv * 4 + (lane >> 4);    // 4 nodes per wave
    if (node >= n) return;

    uint4 us = G[(size_t)node * 16 + hl];          // self-loop
    float a0[8], a1[8], a2[8], a3[8];
    a0[0] = bflo(us.x); a0[1] = bfhi(us.x); a0[2] = bflo(us.y); a0[3] = bfhi(us.y);
    a0[4] = bflo(us.z); a0[5] = bfhi(us.z); a0[6] = bflo(us.w); a0[7] = bfhi(us.w);
#pragma unroll
    for (int i = 0; i < 8; i++) { a1[i] = 0.f; a2[i] = 0.f; a3[i] = 0.f; }

    int start = offs[node];
    int cnt = deg[node];
    int j = 0;
    for (; j + 4 <= cnt; j += 4) {
        int s0 = srcs[start + j + 0];
        int s1 = srcs[start + j + 1];
        int s2 = srcs[start + j + 2];
        int s3 = srcs[start + j + 3];
        uint4 u0 = G[(size_t)s0 * 16 + hl];
        uint4 u1 = G[(size_t)s1 * 16 + hl];
        uint4 u2 = G[(size_t)s2 * 16 + hl];
        uint4 u3 = G[(size_t)s3 * 16 + hl];
        ACC8(a0, u0) ACC8(a1, u1) ACC8(a2, u2) ACC8(a3, u3)
    }
    for (; j < cnt; j++) {
        int s = srcs[start + j];
        uint4 u = G[(size_t)s * 16 + hl];
        ACC8(a0, u)
    }

    float di = dinv[node];
    const float4* b8 = (const float4*)bias;
    float4 b0 = b8[hl * 2], b1 = b8[hl * 2 + 1];
    float bb[8] = {b0.x, b0.y, b0.z, b0.w, b1.x, b1.y, b1.z, b1.w};
    float r[8];
#pragma unroll
    for (int i = 0; i < 8; i++) {
        float s = (a0[i] + a1[i]) + (a2[i] + a3[i]);
        r[i] = fmaxf(fmaf(s, di, bb[i]), 0.f);
    }
    out[(size_t)node * 16 + hl] =
        make_uint4(pk(r[0], r[1]), pk(r[2], r[3]), pk(r[4], r[5]), pk(r[6], r[7]));
}

#define ACC4(A, U) \
    A[0] += bflo(U.x); A[1] += bfhi(U.x); A[2] += bflo(U.y); A[3] += bfhi(U.y);

// final layer: G bf16 [n][64] = [n][16] uint2; 4 nodes/wave, 4 features/lane.
// log_softmax: 4-wide local + 4 shfl_xor within the 16-lane group; fp32 float4 out.
__global__ __launch_bounds__(256)
void k_agg_softmax(const uint2* __restrict__ G, const int* __restrict__ offs,
                   const int* __restrict__ deg, const int* __restrict__ srcs,
                   const float* __restrict__ dinv, const float* __restrict__ bias,
                   float4* __restrict__ out, int n) {
    int t = blockIdx.x * 256 + threadIdx.x;
    int wv = t >> 6;
    int lane = t & 63;
    int hl = lane & 15;
    int node = wv * 4 + (lane >> 4);
    if (node >= n) return;

    uint2 us = G[(size_t)node * 16 + hl];          // self-loop
    float a0[4], a1[4], a2[4], a3[4];
    a0[0] = bflo(us.x); a0[1] = bfhi(us.x); a0[2] = bflo(us.y); a0[3] = bfhi(us.y);
#pragma unroll
    for (int i = 0; i < 4; i++) { a1[i] = 0.f; a2[i] = 0.f; a3[i] = 0.f; }

    int start = offs[node];
    int cnt = deg[node];
    int j = 0;
    for (; j + 4 <= cnt; j += 4) {
        int s0 = srcs[start + j + 0];
        int s1 = srcs[start + j + 1];
        int s2 = srcs[start + j + 2];
        int s3 = srcs[start + j + 3];
        uint2 u0 = G[(size_t)s0 * 16 + hl];
        uint2 u1 = G[(size_t)s1 * 16 + hl];
        uint2 u2 = G[(size_t)s2 * 16 + hl];
        uint2 u3 = G[(size_t)s3 * 16 + hl];
        ACC4(a0, u0) ACC4(a1, u1) ACC4(a2, u2) ACC4(a3, u3)
    }
    for (; j < cnt; j++) {
        int s = srcs[start + j];
        uint2 u = G[(size_t)s * 16 + hl];
        ACC4(a0, u)
    }

    float di = dinv[node];
    float4 bb = ((const float4*)bias)[hl];
    float t0 = fmaf((a0[0] + a1[0]) + (a2[0] + a3[0]), di, bb.x);
    float t1 = fmaf((a0[1] + a1[1]) + (a2[1] + a3[1]), di, bb.y);
    float t2 = fmaf((a0[2] + a1[2]) + (a2[2] + a3[2]), di, bb.z);
    float t3 = fmaf((a0[3] + a1[3]) + (a2[3] + a3[3]), di, bb.w);
    float m = fmaxf(fmaxf(t0, t1), fmaxf(t2, t3));
#pragma unroll
    for (int off = 1; off < 16; off <<= 1) m = fmaxf(m, __shfl_xor(m, off, 64));
    float e = expf(t0 - m) + expf(t1 - m) + expf(t2 - m) + expf(t3 - m);
#pragma unroll
    for (int off = 1; off < 16; off <<= 1) e += __shfl_xor(e, off, 64);
    float lse = m + logf(e);
    out[(size_t)node * 16 + hl] = make_float4(t0 - lse, t1 - lse, t2 - lse, t3 - lse);
}

// ---------------- launch ----------------

extern "C" void kernel_launch(void* const* d_in, const int* in_sizes, int n_in,
                              void* d_out, int out_size, void* d_ws, size_t ws_size,
                              hipStream_t stream) {
    const float* x  = (const float*)d_in[0];
    const int*   ei = (const int*)d_in[1];
    const int*   row = ei;             // edge_index[0]: source
    const int*   col = ei + NE;        // edge_index[1]: destination
    const float* W1 = (const float*)d_in[2];
    const float* b1 = (const float*)d_in[3];
    const float* W2 = (const float*)d_in[4];
    const float* b2 = (const float*)d_in[5];
    const float* W3 = (const float*)d_in[6];
    const float* b3 = (const float*)d_in[7];
    float* outp = (float*)d_out;

    char* ws = (char*)d_ws;
    size_t off = 0;
    auto alloc = [&](size_t bytes) -> void* {
        void* p = (void*)(ws + off);
        off += (bytes + 255) & ~(size_t)255;
        return p;
    };
    float* dinv  = (float*)alloc((size_t)NN * 4);
    float* bufA  = (float*)alloc((size_t)NN * 128 * 4);   // bf16 G (all layers)
    u16*   bufB  = (u16*)alloc((size_t)NN * 128 * 2);     // bf16 H (layers 2,3)
    int*   deg   = (int*)alloc((size_t)NN * 4);
    int*   offs  = (int*)alloc((size_t)NN * 4);
    int*   cursor= (int*)alloc((size_t)NN * 4);
    int*   bsums = (int*)alloc(1024 * 4);
    int*   srcs  = (int*)alloc((size_t)NE * 4);
    u16*   wp1   = (u16*)alloc(128 * 128 * 2);
    u16*   wp2   = (u16*)alloc(128 * 128 * 2);
    u16*   wp3   = (u16*)alloc(128 * 64 * 2);

    int nbN = (NN + 255) / 256;   // 391
    int nbE = (NE + 255) / 256;

    k_init_deg <<<nbN, 256, 0, stream>>>(deg, NN);
    k_deg_count<<<nbE, 256, 0, stream>>>(col, deg, NE);
    k_dinv     <<<nbN, 256, 0, stream>>>(deg, dinv, NN);
    k_scan1    <<<nbN, 256, 0, stream>>>(deg, offs, bsums, NN);
    k_scan2    <<<1,   512, 0, stream>>>(bsums, nbN);
    k_scan3    <<<nbN, 256, 0, stream>>>(offs, bsums, cursor, NN);
    k_fill     <<<nbE, 256, 0, stream>>>(row, col, cursor, srcs, NE);

    k_pack_w<128><<<64, 256, 0, stream>>>(W1, wp1);
    k_pack_w<128><<<64, 256, 0, stream>>>(W2, wp2);
    k_pack_w<64> <<<32, 256, 0, stream>>>(W3, wp3);

    int gb = (NN + 63) / 64;                    // 1563
    int ab4 = ((NN + 3) / 4 * 64 + 255) / 256;  // 4 nodes/wave -> 6250 blocks

    // layer 1: x(fp32, inline cvt) -> bufA(bf16 G) -> bufB(bf16 h1)
    k_gemm_mfma<128, true, true><<<gb, 256, 0, stream>>>(x, wp1, dinv, bufA, NN);
    k_agg_relu <<<ab4, 256, 0, stream>>>((uint4*)bufA, offs, deg, srcs, dinv, b1, (uint4*)bufB, NN);
    // layer 2: bufB -> bufA(bf16 G) -> bufB(bf16 h2)
    k_gemm_mfma<128, true, false><<<gb, 256, 0, stream>>>(bufB, wp2, dinv, bufA, NN);
    k_agg_relu <<<ab4, 256, 0, stream>>>((uint4*)bufA, offs, deg, srcs, dinv, b2, (uint4*)bufB, NN);
    // layer 3: bufB -> bufA(bf16 G, 64-wide) -> out (log_softmax)
    k_gemm_mfma<64, true, false><<<gb, 256, 0, stream>>>(bufB, wp3, dinv, bufA, NN);
    k_agg_softmax<<<ab4, 256, 0, stream>>>((uint2*)bufA, offs, deg, srcs, dinv, b3, (float4*)outp, NN);
}